// Round 1
// baseline (1482.162 us; speedup 1.0000x reference)
//
#include <hip/hip_runtime.h>
#include <hip/hip_bf16.h>

// Problem constants (fixed by the reference): N=50000, E=800000
// x:[N,256] ei:[2,E] W1:[256,128] b1:[128] W2:[128,12] b2:[12]
// L1:[12,512] lb1:[512] L2:[512,512] lb2:[512] L3:[512,2] lb3:[2]
// out:[N,2] fp32

// ---------------- degree / dinv ----------------
__global__ void k_deg_init(float* __restrict__ deg, int n) {
    int i = blockIdx.x * blockDim.x + threadIdx.x;
    if (i < n) deg[i] = 1.0f;   // self-loop
}

__global__ void k_deg_accum(const int* __restrict__ col, float* __restrict__ deg, int e) {
    int i = blockIdx.x * blockDim.x + threadIdx.x;
    if (i < e) atomicAdd(&deg[col[i]], 1.0f);
}

__global__ void k_dinv(float* __restrict__ deg, int n) {
    int i = blockIdx.x * blockDim.x + threadIdx.x;
    if (i < n) deg[i] = 1.0f / sqrtf(deg[i]);   // precise rsqrt
}

// ---------------- GEMM1: t1s = (x @ W1) * dinv[r]; agg1 init = t1s ----------------
// 64 rows x 128 cols per block, K=256 staged in LDS chunks of 64.
__global__ __launch_bounds__(256)
void k_gemm1(const float* __restrict__ A, const float* __restrict__ W,
             const float* __restrict__ dinv, float* __restrict__ t1s,
             float* __restrict__ agg1, int M) {
    __shared__ float xs[64][68];            // +4 pad: 4-row stride -> 2 banks (free)
    const int t  = threadIdx.x;
    const int rb = blockIdx.x * 64;
    const int cg = t & 15, rg = t >> 4;     // 16 col-groups x 16 row-groups
    const int j0 = cg * 8;

    float acc[4][8] = {};
    for (int kk = 0; kk < 256; kk += 64) {
        __syncthreads();
        for (int i = t; i < 1024; i += 256) {       // 64x64 floats = 1024 float4
            int r = i >> 4, q = i & 15;
            float4 v = make_float4(0.f, 0.f, 0.f, 0.f);
            if (rb + r < M)
                v = *(const float4*)(A + (size_t)(rb + r) * 256 + kk + q * 4);
            *(float4*)(&xs[r][q * 4]) = v;
        }
        __syncthreads();
        for (int k = 0; k < 64; ++k) {
            float4 w0 = *(const float4*)(W + (size_t)(kk + k) * 128 + j0);
            float4 w1 = *(const float4*)(W + (size_t)(kk + k) * 128 + j0 + 4);
            float wv[8] = {w0.x, w0.y, w0.z, w0.w, w1.x, w1.y, w1.z, w1.w};
#pragma unroll
            for (int ri = 0; ri < 4; ++ri) {
                float xv = xs[rg * 4 + ri][k];
#pragma unroll
                for (int jj = 0; jj < 8; ++jj)
                    acc[ri][jj] = fmaf(xv, wv[jj], acc[ri][jj]);
            }
        }
    }
#pragma unroll
    for (int ri = 0; ri < 4; ++ri) {
        int r = rb + rg * 4 + ri;
        if (r < M) {
            float dv = dinv[r];
            float4 o0 = make_float4(acc[ri][0] * dv, acc[ri][1] * dv,
                                    acc[ri][2] * dv, acc[ri][3] * dv);
            float4 o1 = make_float4(acc[ri][4] * dv, acc[ri][5] * dv,
                                    acc[ri][6] * dv, acc[ri][7] * dv);
            float* p1 = t1s + (size_t)r * 128 + j0;
            float* p2 = agg1 + (size_t)r * 128 + j0;
            *(float4*)(p1)     = o0;  *(float4*)(p1 + 4) = o1;
            *(float4*)(p2)     = o0;  *(float4*)(p2 + 4) = o1;   // self-loop init
        }
    }
}

// ---------------- scatter1: agg1[col] += t1s[row], 128 feats, wave per edge ----------------
__global__ void k_scatter1(const int* __restrict__ row, const int* __restrict__ col,
                           const float* __restrict__ t1s, float* __restrict__ agg1, int e) {
    const int lane = threadIdx.x & 63;
    const int wpb  = blockDim.x >> 6;
    int w  = blockIdx.x * wpb + (threadIdx.x >> 6);
    int nw = gridDim.x * wpb;
    for (int ed = w; ed < e; ed += nw) {
        int r = row[ed], c = col[ed];
        const float* src = t1s + (size_t)r * 128;
        float* dst = agg1 + (size_t)c * 128;
        atomicAdd(&dst[lane],      src[lane]);
        atomicAdd(&dst[lane + 64], src[lane + 64]);
    }
}

// ---------------- h1 = relu(agg1 * dinv + b1), in place, float4 ----------------
__global__ void k_h1(float* __restrict__ agg1, const float* __restrict__ dinv,
                     const float* __restrict__ b1, int n) {
    int i = blockIdx.x * blockDim.x + threadIdx.x;   // float4 index
    int total = n * 32;                              // n*128/4
    if (i >= total) return;
    int node = i >> 5, q = i & 31;
    float dv = dinv[node];
    float4 v = ((float4*)agg1)[i];
    float4 b = ((const float4*)b1)[q];
    v.x = fmaxf(fmaf(v.x, dv, b.x), 0.f);
    v.y = fmaxf(fmaf(v.y, dv, b.y), 0.f);
    v.z = fmaxf(fmaf(v.z, dv, b.z), 0.f);
    v.w = fmaxf(fmaf(v.w, dv, b.w), 0.f);
    ((float4*)agg1)[i] = v;
}

// ---------------- GEMM2: t2s = (h1 @ W2) * dinv; agg2 init = t2s ----------------
__global__ __launch_bounds__(256)
void k_gemm2(const float* __restrict__ h1, const float* __restrict__ W2,
             const float* __restrict__ dinv, float* __restrict__ t2s,
             float* __restrict__ agg2, int n) {
    __shared__ float ws[128 * 12];
    int t = threadIdx.x;
    for (int i = t; i < 128 * 12; i += 256) ws[i] = W2[i];
    __syncthreads();
    int node = blockIdx.x * 256 + t;
    if (node >= n) return;
    const float4* hp = (const float4*)(h1 + (size_t)node * 128);
    float acc[12] = {};
    for (int k4 = 0; k4 < 32; ++k4) {
        float4 hv = hp[k4];
        float h[4] = {hv.x, hv.y, hv.z, hv.w};
#pragma unroll
        for (int q = 0; q < 4; ++q) {
            int k = k4 * 4 + q;
#pragma unroll
            for (int j = 0; j < 12; ++j)
                acc[j] = fmaf(h[q], ws[k * 12 + j], acc[j]);
        }
    }
    float dv = dinv[node];
    float* p1 = t2s + (size_t)node * 12;
    float* p2 = agg2 + (size_t)node * 12;
#pragma unroll
    for (int j = 0; j < 12; ++j) { float v = acc[j] * dv; p1[j] = v; p2[j] = v; }
}

// ---------------- scatter2: agg2[col] += t2s[row], 12 feats, thread per edge ----------------
__global__ void k_scatter2(const int* __restrict__ row, const int* __restrict__ col,
                           const float* __restrict__ t2s, float* __restrict__ agg2, int e) {
    int i = blockIdx.x * blockDim.x + threadIdx.x;
    if (i >= e) return;
    int r = row[i], c = col[i];
    const float* s = t2s + (size_t)r * 12;
    float* d = agg2 + (size_t)c * 12;
#pragma unroll
    for (int j = 0; j < 12; ++j) atomicAdd(&d[j], s[j]);
}

// ---------------- fused MLP: h2 epilogue -> 12->512 -> 512->512 -> 512->2 ----------------
// 16 nodes per block, 256 threads.
__global__ __launch_bounds__(256)
void k_mlp(const float* __restrict__ agg2, const float* __restrict__ dinv,
           const float* __restrict__ b2,
           const float* __restrict__ L1, const float* __restrict__ lb1,
           const float* __restrict__ L2w, const float* __restrict__ lb2,
           const float* __restrict__ L3, const float* __restrict__ lb3,
           float* __restrict__ out, int n) {
    __shared__ float h2s[16][12];
    __shared__ float h3s[16][512];
    __shared__ float outs[16][2];
    const int t  = threadIdx.x;
    const int nb = blockIdx.x * 16;

    if (t < 192) {
        int ni = t / 12, k = t % 12;
        int node = nb + ni;
        float v = 0.f;
        if (node < n)
            v = fmaxf(fmaf(agg2[(size_t)node * 12 + k], dinv[node], b2[k]), 0.f);
        h2s[ni][k] = v;
    }
    __syncthreads();

    // layer 1: h3 = relu(h2 @ L1 + lb1)  [16][512]
    for (int i = 0; i < 32; ++i) {
        int idx = i * 256 + t;
        int ni = idx >> 9, j = idx & 511;
        float acc = lb1[j];
#pragma unroll
        for (int k = 0; k < 12; ++k)
            acc = fmaf(h2s[ni][k], L1[k * 512 + j], acc);
        h3s[ni][j] = fmaxf(acc, 0.f);
    }
    __syncthreads();

    // layer 2 (+3 fused): 4 nodes x 8 cols per thread
    const int cg = t & 63, ng = t >> 6;
    const int j0 = cg * 8;
    float acc[4][8] = {};
    for (int k = 0; k < 512; ++k) {
        float4 w0 = *(const float4*)(L2w + (size_t)k * 512 + j0);
        float4 w1 = *(const float4*)(L2w + (size_t)k * 512 + j0 + 4);
        float wv[8] = {w0.x, w0.y, w0.z, w0.w, w1.x, w1.y, w1.z, w1.w};
#pragma unroll
        for (int ni = 0; ni < 4; ++ni) {
            float hv = h3s[ng * 4 + ni][k];
#pragma unroll
            for (int jj = 0; jj < 8; ++jj)
                acc[ni][jj] = fmaf(hv, wv[jj], acc[ni][jj]);
        }
    }
    float po[4][2] = {};
#pragma unroll
    for (int jj = 0; jj < 8; ++jj) {
        int j = j0 + jj;
        float2 l3 = *(const float2*)(L3 + j * 2);
        float bb = lb2[j];
#pragma unroll
        for (int ni = 0; ni < 4; ++ni) {
            float h4 = fmaxf(acc[ni][jj] + bb, 0.f);
            po[ni][0] = fmaf(h4, l3.x, po[ni][0]);
            po[ni][1] = fmaf(h4, l3.y, po[ni][1]);
        }
    }
    // reduce across 64 lanes (col-groups)
#pragma unroll
    for (int ofs = 32; ofs; ofs >>= 1) {
#pragma unroll
        for (int ni = 0; ni < 4; ++ni) {
            po[ni][0] += __shfl_xor(po[ni][0], ofs, 64);
            po[ni][1] += __shfl_xor(po[ni][1], ofs, 64);
        }
    }
    if (cg == 0) {
#pragma unroll
        for (int ni = 0; ni < 4; ++ni) {
            outs[ng * 4 + ni][0] = po[ni][0];
            outs[ng * 4 + ni][1] = po[ni][1];
        }
    }
    __syncthreads();
    if (t < 32) {
        int ni = t >> 1, c = t & 1;
        int node = nb + ni;
        if (node < n)
            out[(size_t)node * 2 + c] = outs[ni][c] + lb3[c];
    }
}

extern "C" void kernel_launch(void* const* d_in, const int* in_sizes, int n_in,
                              void* d_out, int out_size, void* d_ws, size_t ws_size,
                              hipStream_t stream) {
    const float* x   = (const float*)d_in[0];
    const int*   ei  = (const int*)d_in[1];
    const float* W1  = (const float*)d_in[2];
    const float* b1  = (const float*)d_in[3];
    const float* W2  = (const float*)d_in[4];
    const float* b2  = (const float*)d_in[5];
    const float* L1  = (const float*)d_in[6];
    const float* lb1 = (const float*)d_in[7];
    const float* L2w = (const float*)d_in[8];
    const float* lb2 = (const float*)d_in[9];
    const float* L3  = (const float*)d_in[10];
    const float* lb3 = (const float*)d_in[11];
    float* out = (float*)d_out;

    const int N = in_sizes[0] / 256;
    const int E = in_sizes[1] / 2;
    const int* rowp = ei;       // edge_index[0]
    const int* colp = ei + E;   // edge_index[1]

    char* ws = (char*)d_ws;
    float* dinv = (float*)ws;                            // N floats (deg then dinv)
    float* t1s  = (float*)(ws + 262144);                 // N*128
    float* agg1 = t1s + (size_t)N * 128;                 // N*128 (becomes h1)
    float* t2s  = agg1 + (size_t)N * 128;                // N*12
    float* agg2 = t2s + (size_t)N * 12;                  // N*12

    k_deg_init <<<(N + 255) / 256, 256, 0, stream>>>(dinv, N);
    k_deg_accum<<<(E + 255) / 256, 256, 0, stream>>>(colp, dinv, E);
    k_dinv     <<<(N + 255) / 256, 256, 0, stream>>>(dinv, N);

    k_gemm1    <<<(N + 63) / 64, 256, 0, stream>>>(x, W1, dinv, t1s, agg1, N);
    k_scatter1 <<<4096, 256, 0, stream>>>(rowp, colp, t1s, agg1, E);
    k_h1       <<<(N * 32 + 255) / 256, 256, 0, stream>>>(agg1, dinv, b1, N);

    k_gemm2    <<<(N + 255) / 256, 256, 0, stream>>>(agg1, W2, dinv, t2s, agg2, N);
    k_scatter2 <<<(E + 255) / 256, 256, 0, stream>>>(rowp, colp, t2s, agg2, E);

    k_mlp      <<<(N + 15) / 16, 256, 0, stream>>>(agg2, dinv, b2, L1, lb1,
                                                   L2w, lb2, L3, lb3, out, N);
}

// Round 2
// 822.434 us; speedup vs baseline: 1.8022x; 1.8022x over previous
//
#include <hip/hip_runtime.h>
#include <hip/hip_bf16.h>

// N=50000, E=800000, F=256
// x:[N,256] ei:[2,E] W1:[256,128] b1:[128] W2:[128,12] b2:[12]
// L1:[12,512] lb1:[512] L2:[512,512] lb2:[512] L3:[512,2] lb3:[2]
// out:[N,2] fp32

// ---------------- CSR build ----------------
__global__ void k_init(int* __restrict__ deg, int* __restrict__ cursor, int n) {
    int i = blockIdx.x * blockDim.x + threadIdx.x;
    if (i < n) { deg[i] = 0; cursor[i] = 0; }
}

__global__ void k_count(const int* __restrict__ col, int* __restrict__ deg, int e) {
    int i = blockIdx.x * blockDim.x + threadIdx.x;
    if (i < e) atomicAdd(&deg[col[i]], 1);
}

__global__ void k_dinv(const int* __restrict__ deg, float* __restrict__ dinv, int n) {
    int i = blockIdx.x * blockDim.x + threadIdx.x;
    if (i < n) dinv[i] = 1.0f / sqrtf((float)deg[i] + 1.0f);  // +1 self-loop
}

// single-block exclusive scan of deg -> off  (n = 50000, 1024 threads)
__global__ __launch_bounds__(1024)
void k_scan(const int* __restrict__ deg, int* __restrict__ off, int n) {
    __shared__ int s[1024];
    int t = threadIdx.x;
    int per = (n + 1023) >> 10;
    int start = t * per, end = min(start + per, n);
    int sum = 0;
    for (int i = start; i < end; ++i) sum += deg[i];
    s[t] = sum;
    __syncthreads();
    for (int d = 1; d < 1024; d <<= 1) {
        int v = (t >= d) ? s[t - d] : 0;
        __syncthreads();
        s[t] += v;
        __syncthreads();
    }
    int base = (t == 0) ? 0 : s[t - 1];
    for (int i = start; i < end; ++i) { off[i] = base; base += deg[i]; }
}

__global__ void k_fill(const int* __restrict__ row, const int* __restrict__ col,
                       const int* __restrict__ off, int* __restrict__ cursor,
                       int* __restrict__ nbr, int e) {
    int i = blockIdx.x * blockDim.x + threadIdx.x;
    if (i < e) {
        int c = col[i];
        int p = atomicAdd(&cursor[c], 1);
        nbr[off[c] + p] = row[i];
    }
}

// ---------------- GEMM1: t1s = (x @ W1) * dinv[r] ----------------
__global__ __launch_bounds__(256)
void k_gemm1(const float* __restrict__ A, const float* __restrict__ W,
             const float* __restrict__ dinv, float* __restrict__ t1s, int M) {
    __shared__ float xs[64][68];
    const int t  = threadIdx.x;
    const int rb = blockIdx.x * 64;
    const int cg = t & 15, rg = t >> 4;
    const int j0 = cg * 8;

    float acc[4][8] = {};
    for (int kk = 0; kk < 256; kk += 64) {
        __syncthreads();
        for (int i = t; i < 1024; i += 256) {
            int r = i >> 4, q = i & 15;
            float4 v = make_float4(0.f, 0.f, 0.f, 0.f);
            if (rb + r < M)
                v = *(const float4*)(A + (size_t)(rb + r) * 256 + kk + q * 4);
            *(float4*)(&xs[r][q * 4]) = v;
        }
        __syncthreads();
        for (int k = 0; k < 64; ++k) {
            float4 w0 = *(const float4*)(W + (size_t)(kk + k) * 128 + j0);
            float4 w1 = *(const float4*)(W + (size_t)(kk + k) * 128 + j0 + 4);
            float wv[8] = {w0.x, w0.y, w0.z, w0.w, w1.x, w1.y, w1.z, w1.w};
#pragma unroll
            for (int ri = 0; ri < 4; ++ri) {
                float xv = xs[rg * 4 + ri][k];
#pragma unroll
                for (int jj = 0; jj < 8; ++jj)
                    acc[ri][jj] = fmaf(xv, wv[jj], acc[ri][jj]);
            }
        }
    }
#pragma unroll
    for (int ri = 0; ri < 4; ++ri) {
        int r = rb + rg * 4 + ri;
        if (r < M) {
            float dv = dinv[r];
            float4 o0 = make_float4(acc[ri][0] * dv, acc[ri][1] * dv,
                                    acc[ri][2] * dv, acc[ri][3] * dv);
            float4 o1 = make_float4(acc[ri][4] * dv, acc[ri][5] * dv,
                                    acc[ri][6] * dv, acc[ri][7] * dv);
            float* p1 = t1s + (size_t)r * 128 + j0;
            *(float4*)(p1)     = o0;  *(float4*)(p1 + 4) = o1;
        }
    }
}

// ---------------- gather1 + h1 epilogue: h1[c] = relu(dinv[c]*(t1s[c]+Σ t1s[nbr])+b1) ----------------
// one wave per node, lane = 2 features
__global__ __launch_bounds__(256)
void k_gather1(const int* __restrict__ deg, const int* __restrict__ off,
               const int* __restrict__ nbr, const float* __restrict__ t1s,
               const float* __restrict__ dinv, const float* __restrict__ b1,
               float* __restrict__ h1, int n) {
    const int lane = threadIdx.x & 63;
    const int node = blockIdx.x * 4 + (threadIdx.x >> 6);
    if (node >= n) return;
    const int dg = deg[node];
    const int o  = off[node];
    const int f0 = lane * 2;
    float2 acc = *(const float2*)(t1s + (size_t)node * 128 + f0);  // self-loop
    int i = 0;
    for (; i + 4 <= dg; i += 4) {
        int r0 = nbr[o + i], r1 = nbr[o + i + 1], r2 = nbr[o + i + 2], r3 = nbr[o + i + 3];
        float2 a0 = *(const float2*)(t1s + (size_t)r0 * 128 + f0);
        float2 a1 = *(const float2*)(t1s + (size_t)r1 * 128 + f0);
        float2 a2 = *(const float2*)(t1s + (size_t)r2 * 128 + f0);
        float2 a3 = *(const float2*)(t1s + (size_t)r3 * 128 + f0);
        acc.x += a0.x + a1.x + a2.x + a3.x;
        acc.y += a0.y + a1.y + a2.y + a3.y;
    }
    for (; i < dg; ++i) {
        int r = nbr[o + i];
        float2 a = *(const float2*)(t1s + (size_t)r * 128 + f0);
        acc.x += a.x; acc.y += a.y;
    }
    float dv = dinv[node];
    float2 b = *(const float2*)(b1 + f0);
    float2 hv;
    hv.x = fmaxf(fmaf(acc.x, dv, b.x), 0.f);
    hv.y = fmaxf(fmaf(acc.y, dv, b.y), 0.f);
    *(float2*)(h1 + (size_t)node * 128 + f0) = hv;
}

// ---------------- GEMM2: t2s = (h1 @ W2) * dinv ----------------
__global__ __launch_bounds__(256)
void k_gemm2(const float* __restrict__ h1, const float* __restrict__ W2,
             const float* __restrict__ dinv, float* __restrict__ t2s, int n) {
    __shared__ float ws[128 * 12];
    int t = threadIdx.x;
    for (int i = t; i < 128 * 12; i += 256) ws[i] = W2[i];
    __syncthreads();
    int node = blockIdx.x * 256 + t;
    if (node >= n) return;
    const float4* hp = (const float4*)(h1 + (size_t)node * 128);
    float acc[12] = {};
    for (int k4 = 0; k4 < 32; ++k4) {
        float4 hv = hp[k4];
        float h[4] = {hv.x, hv.y, hv.z, hv.w};
#pragma unroll
        for (int q = 0; q < 4; ++q) {
            int k = k4 * 4 + q;
#pragma unroll
            for (int j = 0; j < 12; ++j)
                acc[j] = fmaf(h[q], ws[k * 12 + j], acc[j]);
        }
    }
    float dv = dinv[node];
    float* p1 = t2s + (size_t)node * 12;
#pragma unroll
    for (int j = 0; j < 12; ++j) p1[j] = acc[j] * dv;
}

// ---------------- fused: gather2 + h2 -> 12->512 -> 512->512 -> 512->2 ----------------
// 16 nodes per block, 256 threads.
__global__ __launch_bounds__(256)
void k_mlp(const int* __restrict__ deg, const int* __restrict__ off,
           const int* __restrict__ nbr, const float* __restrict__ t2s,
           const float* __restrict__ dinv, const float* __restrict__ b2,
           const float* __restrict__ L1, const float* __restrict__ lb1,
           const float* __restrict__ L2w, const float* __restrict__ lb2,
           const float* __restrict__ L3, const float* __restrict__ lb3,
           float* __restrict__ out, int n) {
    __shared__ float h2s[16][12];
    __shared__ float h3s[16][512];
    __shared__ float outs[16][2];
    const int t  = threadIdx.x;
    const int nb = blockIdx.x * 16;

    // gather2 + h2 epilogue: thread (ni, j) for ni<16, j<12
    if (t < 192) {
        int ni = t / 12, j = t % 12;
        int node = nb + ni;
        float v = 0.f;
        if (node < n) {
            int dg = deg[node], o = off[node];
            float acc = t2s[(size_t)node * 12 + j];   // self-loop
            for (int i = 0; i < dg; ++i) {
                int r = nbr[o + i];
                acc += t2s[(size_t)r * 12 + j];
            }
            v = fmaxf(fmaf(acc, dinv[node], b2[j]), 0.f);
        }
        h2s[ni][j] = v;
    }
    __syncthreads();

    // layer 1: h3 = relu(h2 @ L1 + lb1)  [16][512]
    for (int i = 0; i < 32; ++i) {
        int idx = i * 256 + t;
        int ni = idx >> 9, j = idx & 511;
        float acc = lb1[j];
#pragma unroll
        for (int k = 0; k < 12; ++k)
            acc = fmaf(h2s[ni][k], L1[k * 512 + j], acc);
        h3s[ni][j] = fmaxf(acc, 0.f);
    }
    __syncthreads();

    // layer 2 (+3 fused): 4 nodes x 8 cols per thread
    const int cg = t & 63, ng = t >> 6;
    const int j0 = cg * 8;
    float acc[4][8] = {};
    for (int k = 0; k < 512; ++k) {
        float4 w0 = *(const float4*)(L2w + (size_t)k * 512 + j0);
        float4 w1 = *(const float4*)(L2w + (size_t)k * 512 + j0 + 4);
        float wv[8] = {w0.x, w0.y, w0.z, w0.w, w1.x, w1.y, w1.z, w1.w};
#pragma unroll
        for (int ni = 0; ni < 4; ++ni) {
            float hv = h3s[ng * 4 + ni][k];
#pragma unroll
            for (int jj = 0; jj < 8; ++jj)
                acc[ni][jj] = fmaf(hv, wv[jj], acc[ni][jj]);
        }
    }
    float po[4][2] = {};
#pragma unroll
    for (int jj = 0; jj < 8; ++jj) {
        int j = j0 + jj;
        float2 l3 = *(const float2*)(L3 + j * 2);
        float bb = lb2[j];
#pragma unroll
        for (int ni = 0; ni < 4; ++ni) {
            float h4 = fmaxf(acc[ni][jj] + bb, 0.f);
            po[ni][0] = fmaf(h4, l3.x, po[ni][0]);
            po[ni][1] = fmaf(h4, l3.y, po[ni][1]);
        }
    }
#pragma unroll
    for (int ofs = 32; ofs; ofs >>= 1) {
#pragma unroll
        for (int ni = 0; ni < 4; ++ni) {
            po[ni][0] += __shfl_xor(po[ni][0], ofs, 64);
            po[ni][1] += __shfl_xor(po[ni][1], ofs, 64);
        }
    }
    if (cg == 0) {
#pragma unroll
        for (int ni = 0; ni < 4; ++ni) {
            outs[ng * 4 + ni][0] = po[ni][0];
            outs[ng * 4 + ni][1] = po[ni][1];
        }
    }
    __syncthreads();
    if (t < 32) {
        int ni = t >> 1, c = t & 1;
        int node = nb + ni;
        if (node < n)
            out[(size_t)node * 2 + c] = outs[ni][c] + lb3[c];
    }
}

extern "C" void kernel_launch(void* const* d_in, const int* in_sizes, int n_in,
                              void* d_out, int out_size, void* d_ws, size_t ws_size,
                              hipStream_t stream) {
    const float* x   = (const float*)d_in[0];
    const int*   ei  = (const int*)d_in[1];
    const float* W1  = (const float*)d_in[2];
    const float* b1  = (const float*)d_in[3];
    const float* W2  = (const float*)d_in[4];
    const float* b2  = (const float*)d_in[5];
    const float* L1  = (const float*)d_in[6];
    const float* lb1 = (const float*)d_in[7];
    const float* L2w = (const float*)d_in[8];
    const float* lb2 = (const float*)d_in[9];
    const float* L3  = (const float*)d_in[10];
    const float* lb3 = (const float*)d_in[11];
    float* out = (float*)d_out;

    const int N = in_sizes[0] / 256;
    const int E = in_sizes[1] / 2;
    const int* rowp = ei;       // edge_index[0]
    const int* colp = ei + E;   // edge_index[1]

    char* ws = (char*)d_ws;
    int*   deg    = (int*)ws;                       // N
    int*   cursor = deg + N;                        // N
    int*   offp   = cursor + N;                     // N
    float* dinv   = (float*)(offp + N);             // N
    int*   nbr    = (int*)(dinv + N);               // E
    float* t1s    = (float*)(nbr + E);              // N*128
    float* h1     = t1s + (size_t)N * 128;          // N*128
    float* t2s    = h1 + (size_t)N * 128;           // N*12

    k_init  <<<(N + 255) / 256, 256, 0, stream>>>(deg, cursor, N);
    k_count <<<(E + 255) / 256, 256, 0, stream>>>(colp, deg, E);
    k_dinv  <<<(N + 255) / 256, 256, 0, stream>>>(deg, dinv, N);
    k_scan  <<<1, 1024, 0, stream>>>(deg, offp, N);
    k_fill  <<<(E + 255) / 256, 256, 0, stream>>>(rowp, colp, offp, cursor, nbr, E);

    k_gemm1   <<<(N + 63) / 64, 256, 0, stream>>>(x, W1, dinv, t1s, N);
    k_gather1 <<<(N + 3) / 4, 256, 0, stream>>>(deg, offp, nbr, t1s, dinv, b1, h1, N);
    k_gemm2   <<<(N + 255) / 256, 256, 0, stream>>>(h1, W2, dinv, t2s, N);
    k_mlp     <<<(N + 15) / 16, 256, 0, stream>>>(deg, offp, nbr, t2s, dinv, b2,
                                                  L1, lb1, L2w, lb2, L3, lb3, out, N);
}